// Round 15
// baseline (348.818 us; speedup 1.0000x reference)
//
#include <hip/hip_runtime.h>
#include <hip/hip_bf16.h>

static constexpr int VN = 500000;   // nodes
static constexpr int DD = 128;      // feature dim
static constexpr int NE = 1000000;  // hyperedges
static constexpr int KE = 8;        // nodes per hyperedge
static constexpr int CC = 16;       // layer-3 width
static constexpr int H1 = 8;        // hidden width
// deg[v] <= incidence ~ Poisson(16)/side; max over 500k nodes ~45. EW=32 OVERFLOWED (R7/R8).
static constexpr int EW = 64;
static constexpr int TR = 64;       // rows staged per k_row block
static constexpr int LSTR = 129;    // LDS row stride (+1 pad: bank (t+j)%32, conflict-free)

typedef float fvec4 __attribute__((ext_vector_type(4)));
typedef int   ivec4 __attribute__((ext_vector_type(4)));

// LDS-staged k_row, 4-wave compute: 256 threads stage 64 rows coalesced;
// thread t computes row (t&63), j-quarter (t>>6) -> each wave has uniform q,
// so W1/rv stay scalar s_loads. Partials parked in own LDS segment, lanes
// 0..63 reduce 4 partials after one barrier.
__global__ __launch_bounds__(256) void k_row(const float* __restrict__ X,
                                             const float* __restrict__ rv,
                                             const float* __restrict__ W1,
                                             float* __restrict__ proj,
                                             float* __restrict__ A,
                                             int* __restrict__ fill) {
    __shared__ float xs[TR * LSTR];   // 33 KB
    int v0 = blockIdx.x * TR;
    int tid = threadIdx.x;
    int nrows = min(TR, VN - v0);
    int totalF4 = nrows * (DD / 4);
    const float4* X4 = reinterpret_cast<const float4*>(X) + (size_t)v0 * (DD / 4);
#pragma unroll 8
    for (int i = tid; i < totalF4; i += 256) {
        float4 t = X4[i];
        int r = i >> 5;
        int c = (i & 31) << 2;
        float* dst = &xs[r * LSTR + c];
        dst[0] = t.x; dst[1] = t.y; dst[2] = t.z; dst[3] = t.w;
    }
    __syncthreads();
    int r = tid & 63;
    int q = tid >> 6;                 // wave-uniform quarter
    if (r < nrows) {
        float accP = 0.f;
        float accM[H1];
#pragma unroll
        for (int j = 0; j < H1; ++j) accM[j] = 0.f;
        const float* xrow = &xs[r * LSTR + q * 32];
        const float* rvq = rv + q * 32;
        const float* W1q = W1 + (size_t)(q * 32) * H1;
#pragma unroll 8
        for (int j = 0; j < 32; ++j) {
            float x = xrow[j];
            accP += x * rvq[j];       // uniform -> scalar load
            const float4* wr = reinterpret_cast<const float4*>(W1q + (size_t)j * H1);
            float4 wa = wr[0], wb = wr[1];   // uniform -> s_load
            accM[0] += x * wa.x; accM[1] += x * wa.y;
            accM[2] += x * wa.z; accM[3] += x * wa.w;
            accM[4] += x * wb.x; accM[5] += x * wb.y;
            accM[6] += x * wb.z; accM[7] += x * wb.w;
        }
        // park partials in own segment (only this thread touches it)
        float* dst = &xs[r * LSTR + q * 32];
        dst[0] = accP;
#pragma unroll
        for (int j = 0; j < H1; ++j) dst[1 + j] = accM[j];
    }
    __syncthreads();
    int v = v0 + tid;
    if (tid >= nrows || v >= VN) return;   // waves 1..3 retire
    float sP = 0.f;
    float sM[H1];
#pragma unroll
    for (int j = 0; j < H1; ++j) sM[j] = 0.f;
#pragma unroll
    for (int q2 = 0; q2 < 4; ++q2) {
        const float* src = &xs[tid * LSTR + q2 * 32];   // bank (tid+k)%32: 2-way, free
        sP += src[0];
#pragma unroll
        for (int j = 0; j < H1; ++j) sM[j] += src[1 + j];
    }
    proj[v] = sP;
    fill[v] = 0;
    float4* a4 = reinterpret_cast<float4*>(A + (size_t)v * H1);
    a4[0] = make_float4(sM[0], sM[1], sM[2], sM[3]);
    a4[1] = make_float4(sM[4], sM[5], sM[6], sM[7]);
}

// Per-edge argmax/argmin (first occurrence wins) + TRANSPOSED ELL place.
__global__ __launch_bounds__(256) void k_place(const int* __restrict__ E,
                                               const float* __restrict__ proj,
                                               int* __restrict__ fill,
                                               int* __restrict__ ell) {
    int e = blockIdx.x * 256 + threadIdx.x;
    if (e >= NE) return;
    const ivec4* er = reinterpret_cast<const ivec4*>(E + (size_t)e * KE);
    ivec4 e0 = __builtin_nontemporal_load(&er[0]);
    ivec4 e1 = __builtin_nontemporal_load(&er[1]);
    int ids[KE] = {e0.x, e0.y, e0.z, e0.w, e1.x, e1.y, e1.z, e1.w};
    float p[KE];
#pragma unroll
    for (int j = 0; j < KE; ++j) p[j] = proj[ids[j]];
    float bestMax = p[0], bestMin = p[0];
    int idMax = ids[0], idMin = ids[0];
#pragma unroll
    for (int j = 1; j < KE; ++j) {
        if (p[j] > bestMax) { bestMax = p[j]; idMax = ids[j]; }
        if (p[j] < bestMin) { bestMin = p[j]; idMin = ids[j]; }
    }
    int ps = atomicAdd(fill + idMax, 1);
    int pi = atomicAdd(fill + idMin, 1);
    if (ps < EW) __builtin_nontemporal_store(idMin, ell + (size_t)ps * VN + idMax);
    if (pi < EW) __builtin_nontemporal_store(idMax, ell + (size_t)pi * VN + idMin);
}

// Gather SpMM + bias + ReLU + tiny matmul over TRANSPOSED ELL (R14 structure).
template <int FIN, int FOUT, int RSI, int RSO, bool PRE>
__global__ __launch_bounds__(256) void k_glayer(const int* __restrict__ ell,
                                                const int* __restrict__ fill,
                                                const float* __restrict__ bias,
                                                const float* __restrict__ W,
                                                const float* __restrict__ Min,
                                                float* __restrict__ Mout) {
    int v = blockIdx.x * 256 + threadIdx.x;
    if (v >= VN) return;
    int deg = fill[v];
    float di = rsqrtf(1.0f + 0.125f * (float)deg);
    deg = min(deg, EW);   // defensive: never walk past plane EW-1
    float s[FIN];
#pragma unroll
    for (int j = 0; j < FIN; ++j) s[j] = 0.f;
    const int* colv = ell + v;        // plane stride = VN
    int p = 0;
    for (; p + 4 <= deg; p += 4) {
        int c0 = colv[(size_t)(p + 0) * VN];
        int c1 = colv[(size_t)(p + 1) * VN];
        int c2 = colv[(size_t)(p + 2) * VN];
        int c3 = colv[(size_t)(p + 3) * VN];
        float sc0 = 1.f, sc1 = 1.f, sc2 = 1.f, sc3 = 1.f;
        if (!PRE) {
            sc0 = rsqrtf(1.0f + 0.125f * (float)fill[c0]);
            sc1 = rsqrtf(1.0f + 0.125f * (float)fill[c1]);
            sc2 = rsqrtf(1.0f + 0.125f * (float)fill[c2]);
            sc3 = rsqrtf(1.0f + 0.125f * (float)fill[c3]);
        }
        const float4* r0 = reinterpret_cast<const float4*>(Min + (size_t)c0 * RSI);
        const float4* r1 = reinterpret_cast<const float4*>(Min + (size_t)c1 * RSI);
        const float4* r2 = reinterpret_cast<const float4*>(Min + (size_t)c2 * RSI);
        const float4* r3 = reinterpret_cast<const float4*>(Min + (size_t)c3 * RSI);
        float4 t0[FIN / 4], t1[FIN / 4], t2[FIN / 4], t3[FIN / 4];
#pragma unroll
        for (int j = 0; j < FIN / 4; ++j) t0[j] = r0[j];
#pragma unroll
        for (int j = 0; j < FIN / 4; ++j) t1[j] = r1[j];
#pragma unroll
        for (int j = 0; j < FIN / 4; ++j) t2[j] = r2[j];
#pragma unroll
        for (int j = 0; j < FIN / 4; ++j) t3[j] = r3[j];
#pragma unroll
        for (int j = 0; j < FIN / 4; ++j) {
            s[4 * j]     += sc0 * t0[j].x + sc1 * t1[j].x + sc2 * t2[j].x + sc3 * t3[j].x;
            s[4 * j + 1] += sc0 * t0[j].y + sc1 * t1[j].y + sc2 * t2[j].y + sc3 * t3[j].y;
            s[4 * j + 2] += sc0 * t0[j].z + sc1 * t1[j].z + sc2 * t2[j].z + sc3 * t3[j].z;
            s[4 * j + 3] += sc0 * t0[j].w + sc1 * t1[j].w + sc2 * t2[j].w + sc3 * t3[j].w;
        }
    }
    for (; p < deg; ++p) {
        int c = colv[(size_t)p * VN];
        float sc = 1.f;
        if (!PRE) sc = rsqrtf(1.0f + 0.125f * (float)fill[c]);
        const float4* cr = reinterpret_cast<const float4*>(Min + (size_t)c * RSI);
#pragma unroll
        for (int j = 0; j < FIN / 4; ++j) {
            float4 t = cr[j];
            s[4 * j] += sc * t.x; s[4 * j + 1] += sc * t.y;
            s[4 * j + 2] += sc * t.z; s[4 * j + 3] += sc * t.w;
        }
    }
    const float4* mr = reinterpret_cast<const float4*>(Min + (size_t)v * RSI);
    float own[FIN];
#pragma unroll
    for (int j = 0; j < FIN / 4; ++j) {
        float4 t = mr[j];
        own[4 * j] = t.x; own[4 * j + 1] = t.y;
        own[4 * j + 2] = t.z; own[4 * j + 3] = t.w;
    }
    float osc = PRE ? 1.0f : di;
    float h[FIN];
#pragma unroll
    for (int j = 0; j < FIN; ++j) {
        float y = di * (osc * own[j] + 0.125f * s[j]) + bias[j];
        h[j] = y > 0.f ? y : 0.f;
    }
#pragma unroll
    for (int c = 0; c < FOUT; ++c) {
        float m = 0.f;
#pragma unroll
        for (int j = 0; j < FIN; ++j) m += h[j] * W[j * FOUT + c];
        Mout[(size_t)v * RSO + c] = di * m;
    }
}

// Final: transposed-ELL gather of Y3 (PRE rows, RS=16), relu, head, sigmoid
__global__ __launch_bounds__(256) void k_gfinal(const int* __restrict__ ell,
                                                const int* __restrict__ fill,
                                                const float* __restrict__ b3,
                                                const float* __restrict__ fcw,
                                                const float* __restrict__ fcb,
                                                const float* __restrict__ Min,
                                                float* __restrict__ out) {
    int v = blockIdx.x * 256 + threadIdx.x;
    if (v >= VN) return;
    int deg = fill[v];
    float di = rsqrtf(1.0f + 0.125f * (float)deg);
    deg = min(deg, EW);
    float s[CC];
#pragma unroll
    for (int j = 0; j < CC; ++j) s[j] = 0.f;
    const int* colv = ell + v;
    int p = 0;
    for (; p + 2 <= deg; p += 2) {
        int c0 = colv[(size_t)(p + 0) * VN];
        int c1 = colv[(size_t)(p + 1) * VN];
        const float4* r0 = reinterpret_cast<const float4*>(Min + (size_t)c0 * CC);
        const float4* r1 = reinterpret_cast<const float4*>(Min + (size_t)c1 * CC);
        float4 t0[CC / 4], t1[CC / 4];
#pragma unroll
        for (int j = 0; j < CC / 4; ++j) t0[j] = r0[j];
#pragma unroll
        for (int j = 0; j < CC / 4; ++j) t1[j] = r1[j];
#pragma unroll
        for (int j = 0; j < CC / 4; ++j) {
            s[4 * j]     += t0[j].x + t1[j].x;
            s[4 * j + 1] += t0[j].y + t1[j].y;
            s[4 * j + 2] += t0[j].z + t1[j].z;
            s[4 * j + 3] += t0[j].w + t1[j].w;
        }
    }
    if (p < deg) {
        int c = colv[(size_t)p * VN];
        const float4* cr = reinterpret_cast<const float4*>(Min + (size_t)c * CC);
#pragma unroll
        for (int j = 0; j < CC / 4; ++j) {
            float4 t = cr[j];
            s[4 * j] += t.x; s[4 * j + 1] += t.y;
            s[4 * j + 2] += t.z; s[4 * j + 3] += t.w;
        }
    }
    const float4* mr = reinterpret_cast<const float4*>(Min + (size_t)v * CC);
    float own[CC];
#pragma unroll
    for (int j = 0; j < CC / 4; ++j) {
        float4 t = mr[j];
        own[4 * j] = t.x; own[4 * j + 1] = t.y;
        own[4 * j + 2] = t.z; own[4 * j + 3] = t.w;
    }
    float acc = fcb[0];
#pragma unroll
    for (int j = 0; j < CC; ++j) {
        float y = di * (own[j] + 0.125f * s[j]) + b3[j];
        float hh = y > 0.f ? y : 0.f;
        acc += hh * fcw[j];
    }
    out[v] = 1.f / (1.f + expf(-acc));
}

extern "C" void kernel_launch(void* const* d_in, const int* in_sizes, int n_in,
                              void* d_out, int out_size, void* d_ws, size_t ws_size,
                              hipStream_t stream) {
    const float* X   = (const float*)d_in[0];
    const int*   E   = (const int*)d_in[1];
    const float* rv  = (const float*)d_in[2];
    const float* W1  = (const float*)d_in[3];
    const float* b1  = (const float*)d_in[4];
    const float* W2  = (const float*)d_in[5];
    const float* b2  = (const float*)d_in[6];
    const float* W3  = (const float*)d_in[7];
    const float* b3  = (const float*)d_in[8];
    const float* fcw = (const float*)d_in[9];
    const float* fcb = (const float*)d_in[10];
    float* out = (float*)d_out;

    float* ws = (float*)d_ws;
    float* A    = ws;                          // [VN x 8]  16 MB (raw M1)
    float* B    = ws + 4000000;                // [VN x 8]  16 MB (M2')
    float* C    = ws + 8000000;                // [VN x 16] 32 MB (M3')
    float* proj = ws + 16000000;               // [VN]
    int*   fill = (int*)(ws + 16500000);       // [VN] slot counters == deg
    int*   ell  = (int*)(ws + 17000000);       // [64][VN] transposed, 128 MB

    dim3 blk(256);
    int gR = (VN + TR - 1) / TR;   // 7813 blocks, 64 rows each, 256 threads
    int gV = (VN + 255) / 256;
    int gE = (NE + 255) / 256;

    k_row<<<gR, blk, 0, stream>>>(X, rv, W1, proj, A, fill);
    k_place<<<gE, blk, 0, stream>>>(E, proj, fill, ell);

    // layer 1: A(raw M1,RS8) -> B(M2',RS8)   (neighbor dinv on the fly)
    k_glayer<8, 8, 8, 8, false><<<gV, blk, 0, stream>>>(ell, fill, b1, W2, A, B);
    // layer 2: B(M2',RS8) -> C(M3',RS16)
    k_glayer<8, 16, 8, 16, true><<<gV, blk, 0, stream>>>(ell, fill, b2, W3, B, C);
    // layer 3 + head: C(M3',RS16) -> out
    k_gfinal<<<gV, blk, 0, stream>>>(ell, fill, b3, fcw, fcb, C, out);
}

// Round 16
// 297.574 us; speedup vs baseline: 1.1722x; 1.1722x over previous
//
#include <hip/hip_runtime.h>
#include <hip/hip_bf16.h>

static constexpr int VN = 500000;   // nodes
static constexpr int DD = 128;      // feature dim
static constexpr int NE = 1000000;  // hyperedges
static constexpr int KE = 8;        // nodes per hyperedge
static constexpr int CC = 16;       // layer-3 width
static constexpr int H1 = 8;        // hidden width
// deg[v] <= incidence ~ Poisson(16)/side; max over 500k nodes ~45. EW=32 OVERFLOWED (R7/R8).
static constexpr int EW = 64;
static constexpr int TR = 64;       // rows staged per k_row block
static constexpr int LSTR = 129;    // LDS row stride (+1 pad: bank (t+j)%32, conflict-free)

typedef float fvec4 __attribute__((ext_vector_type(4)));
typedef int   ivec4 __attribute__((ext_vector_type(4)));

// LDS-staged k_row (R13/R14 structure, ~81us — R10/R15 restructures both lost):
// 256 threads stage 64 rows coalesced; lanes 0..63 compute one row each with
// thread-uniform (scalar) W1/rv loads.
__global__ __launch_bounds__(256) void k_row(const float* __restrict__ X,
                                             const float* __restrict__ rv,
                                             const float* __restrict__ W1,
                                             float* __restrict__ proj,
                                             float* __restrict__ A,
                                             int* __restrict__ fill) {
    __shared__ float xs[TR * LSTR];   // 33 KB
    int v0 = blockIdx.x * TR;
    int tid = threadIdx.x;
    int nrows = min(TR, VN - v0);
    int totalF4 = nrows * (DD / 4);
    const float4* X4 = reinterpret_cast<const float4*>(X) + (size_t)v0 * (DD / 4);
#pragma unroll 8
    for (int i = tid; i < totalF4; i += 256) {
        float4 t = X4[i];
        int r = i >> 5;
        int c = (i & 31) << 2;
        float* dst = &xs[r * LSTR + c];
        dst[0] = t.x; dst[1] = t.y; dst[2] = t.z; dst[3] = t.w;
    }
    __syncthreads();
    int v = v0 + tid;
    if (tid >= nrows || v >= VN) return;
    float accP = 0.f;
    float accM[H1];
#pragma unroll
    for (int j = 0; j < H1; ++j) accM[j] = 0.f;
    const float* xrow = &xs[tid * LSTR];
#pragma unroll 8
    for (int j = 0; j < DD; ++j) {
        float x = xrow[j];            // bank (tid + j) % 32 -> conflict-free
        accP += x * rv[j];            // uniform -> scalar load
        const float4* wr = reinterpret_cast<const float4*>(W1 + (size_t)j * H1);
        float4 wa = wr[0], wb = wr[1];   // uniform -> s_load
        accM[0] += x * wa.x; accM[1] += x * wa.y;
        accM[2] += x * wa.z; accM[3] += x * wa.w;
        accM[4] += x * wb.x; accM[5] += x * wb.y;
        accM[6] += x * wb.z; accM[7] += x * wb.w;
    }
    proj[v] = accP;
    fill[v] = 0;
    float4* a4 = reinterpret_cast<float4*>(A + (size_t)v * H1);
    a4[0] = make_float4(accM[0], accM[1], accM[2], accM[3]);
    a4[1] = make_float4(accM[4], accM[5], accM[6], accM[7]);
}

// Per-edge argmax/argmin (first occurrence wins) + TRANSPOSED ELL place.
__global__ __launch_bounds__(256) void k_place(const int* __restrict__ E,
                                               const float* __restrict__ proj,
                                               int* __restrict__ fill,
                                               int* __restrict__ ell) {
    int e = blockIdx.x * 256 + threadIdx.x;
    if (e >= NE) return;
    const ivec4* er = reinterpret_cast<const ivec4*>(E + (size_t)e * KE);
    ivec4 e0 = __builtin_nontemporal_load(&er[0]);
    ivec4 e1 = __builtin_nontemporal_load(&er[1]);
    int ids[KE] = {e0.x, e0.y, e0.z, e0.w, e1.x, e1.y, e1.z, e1.w};
    float p[KE];
#pragma unroll
    for (int j = 0; j < KE; ++j) p[j] = proj[ids[j]];
    float bestMax = p[0], bestMin = p[0];
    int idMax = ids[0], idMin = ids[0];
#pragma unroll
    for (int j = 1; j < KE; ++j) {
        if (p[j] > bestMax) { bestMax = p[j]; idMax = ids[j]; }
        if (p[j] < bestMin) { bestMin = p[j]; idMin = ids[j]; }
    }
    int ps = atomicAdd(fill + idMax, 1);
    int pi = atomicAdd(fill + idMin, 1);
    if (ps < EW) __builtin_nontemporal_store(idMin, ell + (size_t)ps * VN + idMax);
    if (pi < EW) __builtin_nontemporal_store(idMax, ell + (size_t)pi * VN + idMin);
}

// A *= dinv  (makes layer-1 input PRE-scaled; deletes 2M scattered fill reads
// + 2M rsqrt from the layer-1 gather loop)
__global__ __launch_bounds__(256) void k_scale(const int* __restrict__ fill,
                                               float* __restrict__ A) {
    int v = blockIdx.x * 256 + threadIdx.x;
    if (v >= VN) return;
    float di = rsqrtf(1.0f + 0.125f * (float)fill[v]);
    float4* ar = reinterpret_cast<float4*>(A + (size_t)v * H1);
    float4 a0 = ar[0], a1 = ar[1];
    ar[0] = make_float4(di * a0.x, di * a0.y, di * a0.z, di * a0.w);
    ar[1] = make_float4(di * a1.x, di * a1.y, di * a1.z, di * a1.w);
}

// Gather SpMM + bias + ReLU + tiny matmul over TRANSPOSED ELL (all PRE).
template <int FIN, int FOUT, int RSI, int RSO>
__global__ __launch_bounds__(256) void k_glayer(const int* __restrict__ ell,
                                                const int* __restrict__ fill,
                                                const float* __restrict__ bias,
                                                const float* __restrict__ W,
                                                const float* __restrict__ Min,
                                                float* __restrict__ Mout) {
    int v = blockIdx.x * 256 + threadIdx.x;
    if (v >= VN) return;
    int deg = fill[v];
    float di = rsqrtf(1.0f + 0.125f * (float)deg);
    deg = min(deg, EW);   // defensive: never walk past plane EW-1
    float s[FIN];
#pragma unroll
    for (int j = 0; j < FIN; ++j) s[j] = 0.f;
    const int* colv = ell + v;        // plane stride = VN
    int p = 0;
    for (; p + 4 <= deg; p += 4) {
        int c0 = colv[(size_t)(p + 0) * VN];
        int c1 = colv[(size_t)(p + 1) * VN];
        int c2 = colv[(size_t)(p + 2) * VN];
        int c3 = colv[(size_t)(p + 3) * VN];
        const float4* r0 = reinterpret_cast<const float4*>(Min + (size_t)c0 * RSI);
        const float4* r1 = reinterpret_cast<const float4*>(Min + (size_t)c1 * RSI);
        const float4* r2 = reinterpret_cast<const float4*>(Min + (size_t)c2 * RSI);
        const float4* r3 = reinterpret_cast<const float4*>(Min + (size_t)c3 * RSI);
        float4 t0[FIN / 4], t1[FIN / 4], t2[FIN / 4], t3[FIN / 4];
#pragma unroll
        for (int j = 0; j < FIN / 4; ++j) t0[j] = r0[j];
#pragma unroll
        for (int j = 0; j < FIN / 4; ++j) t1[j] = r1[j];
#pragma unroll
        for (int j = 0; j < FIN / 4; ++j) t2[j] = r2[j];
#pragma unroll
        for (int j = 0; j < FIN / 4; ++j) t3[j] = r3[j];
#pragma unroll
        for (int j = 0; j < FIN / 4; ++j) {
            s[4 * j]     += t0[j].x + t1[j].x + t2[j].x + t3[j].x;
            s[4 * j + 1] += t0[j].y + t1[j].y + t2[j].y + t3[j].y;
            s[4 * j + 2] += t0[j].z + t1[j].z + t2[j].z + t3[j].z;
            s[4 * j + 3] += t0[j].w + t1[j].w + t2[j].w + t3[j].w;
        }
    }
    for (; p < deg; ++p) {
        int c = colv[(size_t)p * VN];
        const float4* cr = reinterpret_cast<const float4*>(Min + (size_t)c * RSI);
#pragma unroll
        for (int j = 0; j < FIN / 4; ++j) {
            float4 t = cr[j];
            s[4 * j] += t.x; s[4 * j + 1] += t.y;
            s[4 * j + 2] += t.z; s[4 * j + 3] += t.w;
        }
    }
    const float4* mr = reinterpret_cast<const float4*>(Min + (size_t)v * RSI);
    float own[FIN];
#pragma unroll
    for (int j = 0; j < FIN / 4; ++j) {
        float4 t = mr[j];
        own[4 * j] = t.x; own[4 * j + 1] = t.y;
        own[4 * j + 2] = t.z; own[4 * j + 3] = t.w;
    }
    float h[FIN];
#pragma unroll
    for (int j = 0; j < FIN; ++j) {
        float y = di * (own[j] + 0.125f * s[j]) + bias[j];
        h[j] = y > 0.f ? y : 0.f;
    }
#pragma unroll
    for (int c = 0; c < FOUT; ++c) {
        float m = 0.f;
#pragma unroll
        for (int j = 0; j < FIN; ++j) m += h[j] * W[j * FOUT + c];
        Mout[(size_t)v * RSO + c] = di * m;
    }
}

// Final: transposed-ELL gather of Y3 (PRE rows, RS=16), 4-wide ILP, head.
__global__ __launch_bounds__(256) void k_gfinal(const int* __restrict__ ell,
                                                const int* __restrict__ fill,
                                                const float* __restrict__ b3,
                                                const float* __restrict__ fcw,
                                                const float* __restrict__ fcb,
                                                const float* __restrict__ Min,
                                                float* __restrict__ out) {
    int v = blockIdx.x * 256 + threadIdx.x;
    if (v >= VN) return;
    int deg = fill[v];
    float di = rsqrtf(1.0f + 0.125f * (float)deg);
    deg = min(deg, EW);
    float s[CC];
#pragma unroll
    for (int j = 0; j < CC; ++j) s[j] = 0.f;
    const int* colv = ell + v;
    int p = 0;
    for (; p + 4 <= deg; p += 4) {
        int c0 = colv[(size_t)(p + 0) * VN];
        int c1 = colv[(size_t)(p + 1) * VN];
        int c2 = colv[(size_t)(p + 2) * VN];
        int c3 = colv[(size_t)(p + 3) * VN];
        const float4* r0 = reinterpret_cast<const float4*>(Min + (size_t)c0 * CC);
        const float4* r1 = reinterpret_cast<const float4*>(Min + (size_t)c1 * CC);
        const float4* r2 = reinterpret_cast<const float4*>(Min + (size_t)c2 * CC);
        const float4* r3 = reinterpret_cast<const float4*>(Min + (size_t)c3 * CC);
        float4 t0[CC / 4], t1[CC / 4], t2[CC / 4], t3[CC / 4];
#pragma unroll
        for (int j = 0; j < CC / 4; ++j) t0[j] = r0[j];
#pragma unroll
        for (int j = 0; j < CC / 4; ++j) t1[j] = r1[j];
#pragma unroll
        for (int j = 0; j < CC / 4; ++j) t2[j] = r2[j];
#pragma unroll
        for (int j = 0; j < CC / 4; ++j) t3[j] = r3[j];
#pragma unroll
        for (int j = 0; j < CC / 4; ++j) {
            s[4 * j]     += t0[j].x + t1[j].x + t2[j].x + t3[j].x;
            s[4 * j + 1] += t0[j].y + t1[j].y + t2[j].y + t3[j].y;
            s[4 * j + 2] += t0[j].z + t1[j].z + t2[j].z + t3[j].z;
            s[4 * j + 3] += t0[j].w + t1[j].w + t2[j].w + t3[j].w;
        }
    }
    for (; p < deg; ++p) {
        int c = colv[(size_t)p * VN];
        const float4* cr = reinterpret_cast<const float4*>(Min + (size_t)c * CC);
#pragma unroll
        for (int j = 0; j < CC / 4; ++j) {
            float4 t = cr[j];
            s[4 * j] += t.x; s[4 * j + 1] += t.y;
            s[4 * j + 2] += t.z; s[4 * j + 3] += t.w;
        }
    }
    const float4* mr = reinterpret_cast<const float4*>(Min + (size_t)v * CC);
    float own[CC];
#pragma unroll
    for (int j = 0; j < CC / 4; ++j) {
        float4 t = mr[j];
        own[4 * j] = t.x; own[4 * j + 1] = t.y;
        own[4 * j + 2] = t.z; own[4 * j + 3] = t.w;
    }
    float acc = fcb[0];
#pragma unroll
    for (int j = 0; j < CC; ++j) {
        float y = di * (own[j] + 0.125f * s[j]) + b3[j];
        float hh = y > 0.f ? y : 0.f;
        acc += hh * fcw[j];
    }
    out[v] = 1.f / (1.f + expf(-acc));
}

extern "C" void kernel_launch(void* const* d_in, const int* in_sizes, int n_in,
                              void* d_out, int out_size, void* d_ws, size_t ws_size,
                              hipStream_t stream) {
    const float* X   = (const float*)d_in[0];
    const int*   E   = (const int*)d_in[1];
    const float* rv  = (const float*)d_in[2];
    const float* W1  = (const float*)d_in[3];
    const float* b1  = (const float*)d_in[4];
    const float* W2  = (const float*)d_in[5];
    const float* b2  = (const float*)d_in[6];
    const float* W3  = (const float*)d_in[7];
    const float* b3  = (const float*)d_in[8];
    const float* fcw = (const float*)d_in[9];
    const float* fcb = (const float*)d_in[10];
    float* out = (float*)d_out;

    float* ws = (float*)d_ws;
    float* A    = ws;                          // [VN x 8]  16 MB (M1 -> M1')
    float* B    = ws + 4000000;                // [VN x 8]  16 MB (M2')
    float* C    = ws + 8000000;                // [VN x 16] 32 MB (M3')
    float* proj = ws + 16000000;               // [VN]
    int*   fill = (int*)(ws + 16500000);       // [VN] slot counters == deg
    int*   ell  = (int*)(ws + 17000000);       // [64][VN] transposed, 128 MB

    dim3 blk(256);
    int gR = (VN + TR - 1) / TR;   // 7813 blocks, 64 rows each, 256 threads
    int gV = (VN + 255) / 256;
    int gE = (NE + 255) / 256;

    k_row<<<gR, blk, 0, stream>>>(X, rv, W1, proj, A, fill);
    k_place<<<gE, blk, 0, stream>>>(E, proj, fill, ell);
    k_scale<<<gV, blk, 0, stream>>>(fill, A);

    // layer 1: A(M1',RS8) -> B(M2',RS8)
    k_glayer<8, 8, 8, 8><<<gV, blk, 0, stream>>>(ell, fill, b1, W2, A, B);
    // layer 2: B(M2',RS8) -> C(M3',RS16)
    k_glayer<8, 16, 8, 16><<<gV, blk, 0, stream>>>(ell, fill, b2, W3, B, C);
    // layer 3 + head: C(M3',RS16) -> out
    k_gfinal<<<gV, blk, 0, stream>>>(ell, fill, b3, fcw, fcb, C, out);
}